// Round 5
// baseline (219.499 us; speedup 1.0000x reference)
//
#include <hip/hip_runtime.h>

// LaneAttention: per-lane MLP score -> per-group(8) softmax -> weighted pool of
// concat(ht, info, future) into out[32768, 192] fp32.
//
// R7: R4 (scattered, 168 MB fetch) and R6 (coalesced, 99.5 MB fetch) hit the
// SAME 82-84 us -> not bytes-bound. Sustained BW model: in-flight lines/CU =
// waves/CU x per-wave ILP. R2/R4 had waves but no ILP (VGPR 24-28, ~1 load in
// flight); R6 had ILP but 9 waves/CU (53 KB LDS -> 3 blocks). m13's 6.3 TB/s
// copy has both (~80 lines/CU). Now: keep R6's proven coalesced staging +
// swizzled LDS, but (1) split the MLP by hidden unit j (wave w does j=2w,2w+1
// over all 128 dims; ReLU+W2 are per-j, so cross-wave combine is a scalar
// partial score -> hpart 20.5 KB becomes spart 2 KB; LDS 53->34 KB -> 4
// blocks/CU), (2) 512-thread 8-wave blocks -> 4x8 = 32 waves/CU (HW max),
// (3) fut loads hoisted to the top (12 independent VMEM in flight/thread).
// Access patterns (stage, MLP-read, pool-read) identical to R6: 0 conflicts.

__global__ __launch_bounds__(512, 8) void lane_attn_kernel(
    const float* __restrict__ ht,     // [M,64]
    const float* __restrict__ info,   // [M,64]
    const float* __restrict__ fut,    // [M,64]
    const float* __restrict__ W1,     // [128,16]
    const float* __restrict__ b1,     // [16]
    const float* __restrict__ W2,     // [16]
    const float* __restrict__ b2,     // [1]
    const int*   __restrict__ seg,    // [M]
    float*       __restrict__ out)    // [N_GROUPS,192]
{
    const int tid  = threadIdx.x;                                // 0..511
    const int t    = tid & 63;                                   // lane
    const int w    = __builtin_amdgcn_readfirstlane(tid >> 6);   // wave 0..7
    const int base = blockIdx.x * 64;                            // block rows

    // x-tile: 64 rows x 32 16B-slots (s<16: ht quad s; s>=16: info quad s-16),
    // slot stored at s^(row&31) -> every LDS access here is <=2-way (free).
    __shared__ float4 xtile[64 * 32];   // 32 KB
    __shared__ float  spart[8][64];     // 2 KB: per-wave partial scores

    // ---- fut for THIS wave's group (rows 8w..8w+7, col t): 8 independent
    // coalesced 256B loads, issued before everything else (deep VMEM queue).
    float fv[8];
    {
        const float* fp = fut + (size_t)(base + w * 8) * 64 + t;
#pragma unroll
        for (int i = 0; i < 8; ++i) fv[i] = fp[i * 64];
    }

    // ---------------- stage: coalesced global -> swizzled LDS ----------------
    // chunk g = i*512 + tid: (row, s) = (g>>5, g&31). Per wave-instr: 2 rows x
    // 32 slots = two 512B contiguous runs = 16 fully-used lines.
#pragma unroll
    for (int i = 0; i < 4; ++i) {
        const int g   = i * 512 + tid;
        const int row = g >> 5;
        const int s   = g & 31;
        const float* src = (s < 16)
            ? (ht   + (size_t)(base + row) * 64 + s * 4)
            : (info + (size_t)(base + row) * 64 + (s - 16) * 4);
        xtile[row * 32 + (s ^ (row & 31))] = *(const float4*)src;
    }
    __syncthreads();

    // ------------- phase 1: j-pair MLP. Wave w owns hidden units {2w, 2w+1}
    // over ALL 128 dims of row t. W1/b1/W2 indices wave-uniform -> SGPR.
    {
        float h0 = 0.0f, h1 = 0.0f;
        const int j0 = 2 * w;
#pragma unroll
        for (int s = 0; s < 32; ++s) {
            const float4 v  = xtile[t * 32 + (s ^ (t & 31))];
            const int    d0 = s * 4;                 // concat dims d0..d0+3
            h0 = fmaf(v.x, W1[(d0 + 0) * 16 + j0], h0);
            h1 = fmaf(v.x, W1[(d0 + 0) * 16 + j0 + 1], h1);
            h0 = fmaf(v.y, W1[(d0 + 1) * 16 + j0], h0);
            h1 = fmaf(v.y, W1[(d0 + 1) * 16 + j0 + 1], h1);
            h0 = fmaf(v.z, W1[(d0 + 2) * 16 + j0], h0);
            h1 = fmaf(v.z, W1[(d0 + 2) * 16 + j0 + 1], h1);
            h0 = fmaf(v.w, W1[(d0 + 3) * 16 + j0], h0);
            h1 = fmaf(v.w, W1[(d0 + 3) * 16 + j0 + 1], h1);
        }
        // ReLU + W2 are per-j -> this wave's contribution to the score is a
        // scalar; b1 applied here (each j exactly once across waves).
        spart[w][t] = fmaxf(h0 + b1[j0], 0.0f) * W2[j0]
                    + fmaxf(h1 + b1[j0 + 1], 0.0f) * W2[j0 + 1];
    }
    __syncthreads();

    // ------------- score combine + softmax (every wave, row = lane t) -------
    float score = b2[0];
#pragma unroll
    for (int ww = 0; ww < 8; ++ww) score += spart[ww][t];

    float m = score;
    m = fmaxf(m, __shfl_xor(m, 1));
    m = fmaxf(m, __shfl_xor(m, 2));
    m = fmaxf(m, __shfl_xor(m, 4));
    float e = __expf(score - m);
    float s8 = e;
    s8 += __shfl_xor(s8, 1);
    s8 += __shfl_xor(s8, 2);
    s8 += __shfl_xor(s8, 4);
    const float prob = e / s8;   // lane t holds prob of local row t

    // ---------------- phase 2: pooling, ONE group per wave -------------------
    // ht/info from swizzled LDS (2-way max); fut already in registers.
    {
        const int gid = seg[base + w * 8];     // wave-uniform -> scalar load
        const float* xs = (const float*)xtile; // row r = floats [r*128, +128)
        float a0 = 0.0f, a1 = 0.0f, a2 = 0.0f;
#pragma unroll
        for (int i = 0; i < 8; ++i) {
            const int   r = w * 8 + i;
            const float p = __shfl(prob, r);
            const int  sH = (((t >> 2)     ) ^ (r & 31)) * 4 + (t & 3); // ht col t
            const int  sI = (((t >> 2) + 16) ^ (r & 31)) * 4 + (t & 3); // info col t
            a0 = fmaf(p, xs[r * 128 + sH], a0);
            a1 = fmaf(p, xs[r * 128 + sI], a1);
            a2 = fmaf(p, fv[i], a2);
        }
        float* o = out + (size_t)gid * 192;
        o[t]       = a0;
        o[64 + t]  = a1;
        o[128 + t] = a2;
    }
}

extern "C" void kernel_launch(void* const* d_in, const int* in_sizes, int n_in,
                              void* d_out, int out_size, void* d_ws, size_t ws_size,
                              hipStream_t stream) {
    const float* ht   = (const float*)d_in[0];
    const float* info = (const float*)d_in[1];
    const float* fut  = (const float*)d_in[2];
    const float* W1   = (const float*)d_in[3];
    const float* b1   = (const float*)d_in[4];
    const float* W2   = (const float*)d_in[5];
    const float* b2   = (const float*)d_in[6];
    const int*   seg  = (const int*)d_in[7];
    float*       out  = (float*)d_out;

    const int M = in_sizes[7];           // 262144 lanes
    const int blocks = M / 64;           // 4096 blocks x 512 thr, 64 rows each

    lane_attn_kernel<<<blocks, 512, 0, stream>>>(ht, info, fut, W1, b1, W2, b2,
                                                 seg, out);
}